// Round 12
// baseline (154.616 us; speedup 1.0000x reference)
//
#include <hip/hip_runtime.h>

// ---------------------------------------------------------------------------
// MH-MoE, top-2 sparse dispatch, in-register expert FFN.
// B=2 S=2048 H=1024 NH=8 HD=128 T=16384 (32768 tokens) E=8 K=2 F=512
// R12: FFN split-F (1040 blocks: tile x F-half, 8 iters each) -> 2x waves,
// partials in ybufA/ybufB; GEMM2 gather sums 4 streams. Split-K router (R11),
// 128x128 8-wave GEMMs, fused combine in GEMM2.
// ---------------------------------------------------------------------------

typedef __attribute__((ext_vector_type(8))) short bf16x8;
typedef __attribute__((ext_vector_type(4))) float f32x4;
typedef __attribute__((ext_vector_type(16))) float f32x16;
typedef __attribute__((ext_vector_type(4))) unsigned short u16x4;

constexpr int NSLOT = 66560;      // 520 tiles * 128 slots
constexpr int NTILE_MAX = 520;
#define CTRL_CNT 0
#define CTRL_CUR 8

__device__ __forceinline__ unsigned short f2bf(float x) {
  unsigned int u = __float_as_uint(x);
  return (unsigned short)((u + 0x7FFFu + ((u >> 16) & 1u)) >> 16);
}
__device__ __forceinline__ float bf2f(unsigned short u) {
  return __uint_as_float(((unsigned int)u) << 16);
}
__device__ __forceinline__ void gload_lds16(const void* g, void* l) {
  __builtin_amdgcn_global_load_lds(
      (const __attribute__((address_space(1))) unsigned int*)g,
      (__attribute__((address_space(3))) unsigned int*)l, 16, 0, 0);
}

// ---------------- prep: transposes + W1F/W2F + Wcomb ----------------
__global__ __launch_bounds__(256) void prep_all(
    const float* __restrict__ Wmh, unsigned short* __restrict__ Wmh_t,
    const float* __restrict__ Wmg, unsigned short* __restrict__ Wmg_t,
    const float* __restrict__ W1, const float* __restrict__ W2,
    unsigned short* __restrict__ W1F, unsigned short* __restrict__ W2F,
    const float* __restrict__ bmh, const float* __restrict__ Wr,
    float* __restrict__ Wc, int* __restrict__ ctrl) {
  __shared__ float smem[2048];
  const int bid = blockIdx.x, tid = threadIdx.x;
  if (bid < 2048) {
    if (bid == 0 && tid < 16) ctrl[tid] = 0;
    const float* src = (bid < 1024) ? Wmh : Wmg;
    unsigned short* dst = (bid < 1024) ? Wmh_t : Wmg_t;
    const int bb = bid & 1023;
    const int c0 = (bb & 31) * 32, r0 = (bb >> 5) * 32;
    const int tx = tid & 31, ty = tid >> 5;
    float (*tile)[33] = (float(*)[33])smem;
    for (int i = ty; i < 32; i += 8)
      tile[i][tx] = src[(size_t)(r0 + i) * 1024 + c0 + tx];
    __syncthreads();
    for (int i = ty; i < 32; i += 8)
      dst[(size_t)(c0 + i) * 1024 + r0 + tx] = f2bf(tile[tx][i]);
  } else if (bid < 2560) {
    // W1F[e][ft16][kk8][l64][j8], W2F[e][ft16][s2][ht4][l64][j8]
    const int jid = (bid - 2048) * 4 + (tid >> 6);   // 0..2047
    const int l = tid & 63;
    const int is2 = jid >= 1024;
    const int bj = is2 ? jid - 1024 : jid;
    const float* src;
    int C;
    if (!is2) {
      int kk = bj & 7, ft = (bj >> 3) & 15, e = bj >> 7;
      src = W1 + (size_t)e * 65536 + (size_t)(kk * 16) * 512 + ft * 32;
      C = 512;
    } else {
      int sht = bj & 7, ft = (bj >> 3) & 15, e = bj >> 7;
      src = W2 + (size_t)e * 65536 + (size_t)(ft * 32 + (sht >> 2) * 16) * 128 + (sht & 3) * 32;
      C = 128;
    }
    float* tile = smem + (tid >> 6) * 512;   // [16][32]
#pragma unroll
    for (int r = 0; r < 8; ++r) {
      int i = l + 64 * r;
      tile[(i >> 5) * 32 + (i & 31)] = src[(size_t)(i >> 5) * C + (i & 31)];
    }
    __syncthreads();
    int l31 = l & 31, lh = l >> 5;
    bf16x8 v;
#pragma unroll
    for (int j = 0; j < 8; ++j) v[j] = (short)f2bf(tile[(lh * 8 + j) * 32 + l31]);
    unsigned short* dst = is2 ? W2F : W1F;
    *(bf16x8*)(dst + ((size_t)bj * 64 + l) * 8) = v;
  } else {
    const int r = (bid - 2560) * 4 + (tid >> 6);
    if (r > 1024) return;
    const int l = tid & 63;
    const float* src = (r < 1024) ? (Wmh + (size_t)r * 1024) : bmh;
    int nh = l >> 3, e = l & 7;
    float acc = 0.f;
    for (int d = 0; d < 128; ++d) acc = fmaf(src[nh * 128 + d], Wr[d * 8 + e], acc);
    Wc[(size_t)r * 64 + l] = acc;
  }
}

// ---------------- router pass 1: split-K partial logits + x_bf -------------
__global__ __launch_bounds__(256) void router_partial(
    const float* __restrict__ x, const float* __restrict__ Wc,
    float* __restrict__ part, unsigned short* __restrict__ x_bf,
    int* __restrict__ perm, float* __restrict__ gateb) {
  const int tid = threadIdx.x;
  const int kc = blockIdx.x, rb = blockIdx.y;
  int gi = (rb * 8 + kc) * 256 + tid;
  if (gi < NSLOT) { perm[gi] = 0; gateb[gi] = 0.f; }

  __shared__ float xs[32][128];    // 16 KB
  __shared__ float wcs[128][64];   // 32 KB
  const int r0 = rb * 32, k0 = kc * 128;

  for (int f = tid; f < 1024; f += 256) {
    int row = f >> 5, j4 = (f & 31) * 4;
    float4 v = *(const float4*)&x[(size_t)(r0 + row) * 1024 + k0 + j4];
    *(float4*)&xs[row][j4] = v;
    u16x4 o;
    o.x = f2bf(v.x); o.y = f2bf(v.y); o.z = f2bf(v.z); o.w = f2bf(v.w);
    *(u16x4*)&x_bf[(size_t)(r0 + row) * 1024 + k0 + j4] = o;
  }
  {
    const float4* src = (const float4*)(Wc + (size_t)k0 * 64);
    float4* dst = (float4*)&wcs[0][0];
    for (int f = tid; f < 2048; f += 256) dst[f] = src[f];
  }
  __syncthreads();

  const int col = tid & 63, rg = tid >> 6;
  float a[8] = {0.f, 0.f, 0.f, 0.f, 0.f, 0.f, 0.f, 0.f};
  for (int k4 = 0; k4 < 32; ++k4) {
    float4 xv[8];
#pragma unroll
    for (int i = 0; i < 8; ++i)
      xv[i] = *(const float4*)&xs[rg * 8 + i][k4 * 4];
#pragma unroll
    for (int u = 0; u < 4; ++u) {
      float wv = wcs[k4 * 4 + u][col];
#pragma unroll
      for (int i = 0; i < 8; ++i)
        a[i] = fmaf((&xv[i].x)[u], wv, a[i]);
    }
  }
#pragma unroll
  for (int i = 0; i < 8; ++i)
    part[(size_t)kc * 262144 + (size_t)(r0 + rg * 8 + i) * 64 + col] = a[i];
}

// ---------------- router pass 2: fixed-order reduce + top-2 + counts -------
__global__ __launch_bounds__(256) void router_reduce(
    const float* __restrict__ part, const float* __restrict__ Wc,
    int* __restrict__ tok_e, float* __restrict__ tok_g,
    int* __restrict__ ctrl) {
  __shared__ float lg[32][64];
  __shared__ int lcnt[8];
  const int tid = threadIdx.x;
  if (tid < 8) lcnt[tid] = 0;
  const int r0 = blockIdx.x * 32;
  const int col = tid & 63, rg = tid >> 6;
#pragma unroll
  for (int i = 0; i < 8; ++i) {
    size_t base = (size_t)(r0 + rg * 8 + i) * 64 + col;
    float s = Wc[65536 + col];
#pragma unroll
    for (int kc = 0; kc < 8; ++kc) s += part[(size_t)kc * 262144 + base];
    lg[rg * 8 + i][col] = s;
  }
  __syncthreads();
  {
    int row = tid >> 3, nh = tid & 7;
    float l[8];
#pragma unroll
    for (int e = 0; e < 8; ++e) l[e] = lg[row][nh * 8 + e];
    int i1 = 0; float v1 = l[0];
#pragma unroll
    for (int e = 1; e < 8; ++e) if (l[e] > v1) { v1 = l[e]; i1 = e; }
    int i2 = -1; float v2 = -1e30f;
#pragma unroll
    for (int e = 0; e < 8; ++e) if (e != i1 && l[e] > v2) { v2 = l[e]; i2 = e; }
    float g1 = 1.f / (1.f + __expf(v2 - v1));
    float g2 = 1.f - g1;
    size_t t = (size_t)(r0 + row) * 8 + nh;
    tok_e[t * 2] = i1; tok_e[t * 2 + 1] = i2;
    tok_g[t * 2] = g1; tok_g[t * 2 + 1] = g2;
    atomicAdd(&lcnt[i1], 1);
    atomicAdd(&lcnt[i2], 1);
  }
  __syncthreads();
  if (tid < 8 && lcnt[tid])
    atomicAdd(&ctrl[CTRL_CNT + tid], lcnt[tid]);
}

// ---------------- assign (unchanged) ----------------
__global__ __launch_bounds__(256) void assign_kernel(
    const int* __restrict__ tok_e, const float* __restrict__ tok_g,
    int* __restrict__ ctrl, int* __restrict__ perm,
    float* __restrict__ gateb, int* __restrict__ tok_slot) {
  __shared__ int lcnt[8], lbase[8];
  if (threadIdx.x < 8) lcnt[threadIdx.x] = 0;
  __syncthreads();
  int t = blockIdx.x * 256 + threadIdx.x;
  int e0 = tok_e[t * 2], e1 = tok_e[t * 2 + 1];
  int p0 = atomicAdd(&lcnt[e0], 1);
  int p1 = atomicAdd(&lcnt[e1], 1);
  __syncthreads();
  if (threadIdx.x < 8)
    lbase[threadIdx.x] = atomicAdd(&ctrl[CTRL_CUR + threadIdx.x], lcnt[threadIdx.x]);
  __syncthreads();
  int off0 = 0, off1 = 0, acc = 0;
#pragma unroll
  for (int i = 0; i < 8; ++i) {
    int cnt = ctrl[CTRL_CNT + i];
    if (i == e0) off0 = acc;
    if (i == e1) off1 = acc;
    acc += (cnt + 127) & ~127;
  }
  int s0 = off0 + lbase[e0] + p0;
  int s1 = off1 + lbase[e1] + p1;
  perm[s0] = t; perm[s1] = t;
  gateb[s0] = tok_g[t * 2]; gateb[s1] = tok_g[t * 2 + 1];
  tok_slot[t * 2] = s0; tok_slot[t * 2 + 1] = s1;
}

// ---------------- GEMM: C[M][N] = A[M][K](bf16) @ Bt[N][K](bf16)^T + bias --
// 128x128 tile, BK=64, 512 threads = 8 waves, 64KB LDS dbuf.
// A_GATHER=1: A row r, col k = sum of yA/yB at slots s0,s1 (4-way, fp32).
template <int OUT_BF16, int A_GATHER>
__global__ __launch_bounds__(512, 4) void gemm_bt(
    const unsigned short* __restrict__ A, const unsigned short* __restrict__ Bt,
    const float* __restrict__ bias, void* __restrict__ Cout,
    int M, int N, int K,
    const unsigned short* __restrict__ ybufA,
    const unsigned short* __restrict__ ybufB,
    const int* __restrict__ tok_slot) {
  __shared__ __align__(16) unsigned short As[2][128 * 64];
  __shared__ __align__(16) unsigned short Bs[2][128 * 64];
  const int tid = threadIdx.x, lane = tid & 63, w = tid >> 6;
  const int wr = w >> 1, wc = w & 1;
  const int m0 = blockIdx.x * 128, n0 = blockIdx.y * 128;
  const int l15 = lane & 15, lhi = lane >> 4;

  f32x4 acc[2][4];
#pragma unroll
  for (int n = 0; n < 4; ++n) {
    float bv = bias[n0 + wc * 64 + n * 16 + l15];
#pragma unroll
    for (int m = 0; m < 2; ++m) acc[m][n] = (f32x4){bv, bv, bv, bv};
  }

  const int rowi = tid >> 3;       // 0..63
  const int segi = (tid & 7) * 8;  // k offset
  const int NT = K >> 6;

  auto stage = [&](int buf, int kt) {
    const int k0 = kt * 64;
    if constexpr (A_GATHER) {
#pragma unroll
      for (int r = 0; r < 2; ++r) {
        int arow = m0 + r * 64 + rowi;
        int k = k0 + segi;
        int tok = arow * 8 + (k >> 7);
        int hd = k & 127;
        int s0 = tok_slot[tok * 2], s1 = tok_slot[tok * 2 + 1];
        bf16x8 va0 = *(const bf16x8*)(ybufA + (size_t)s0 * 128 + hd);
        bf16x8 vb0 = *(const bf16x8*)(ybufB + (size_t)s0 * 128 + hd);
        bf16x8 va1 = *(const bf16x8*)(ybufA + (size_t)s1 * 128 + hd);
        bf16x8 vb1 = *(const bf16x8*)(ybufB + (size_t)s1 * 128 + hd);
        bf16x8 vs;
#pragma unroll
        for (int j = 0; j < 8; ++j) {
          float p = bf2f((unsigned short)va0[j]) + bf2f((unsigned short)vb0[j]);
          float q = bf2f((unsigned short)va1[j]) + bf2f((unsigned short)vb1[j]);
          vs[j] = (short)f2bf(p + q);
        }
        *(bf16x8*)&As[buf][r * 4096 + tid * 8] = vs;
      }
    } else {
#pragma unroll
      for (int r = 0; r < 2; ++r)
        gload_lds16(A + (size_t)(m0 + r * 64 + rowi) * K + k0 + segi,
                    &As[buf][r * 4096 + w * 512]);
    }
#pragma unroll
    for (int r = 0; r < 2; ++r)
      gload_lds16(Bt + (size_t)(n0 + r * 64 + rowi) * K + k0 + segi,
                  &Bs[buf][r * 4096 + w * 512]);
  };

  stage(0, 0);
  asm volatile("s_waitcnt vmcnt(0)" ::: "memory");
  __syncthreads();
  int cur = 0;
  for (int t = 0; t < NT; ++t) {
    if (t + 1 < NT) stage(cur ^ 1, t + 1);
#pragma unroll
    for (int ks = 0; ks < 64; ks += 32) {
      bf16x8 af[2], bb[4];
#pragma unroll
      for (int m = 0; m < 2; ++m)
        af[m] = *(const bf16x8*)&As[cur][(wr * 32 + m * 16 + l15) * 64 + ks + lhi * 8];
#pragma unroll
      for (int n = 0; n < 4; ++n)
        bb[n] = *(const bf16x8*)&Bs[cur][(wc * 64 + n * 16 + l15) * 64 + ks + lhi * 8];
#pragma unroll
      for (int m = 0; m < 2; ++m)
#pragma unroll
        for (int n = 0; n < 4; ++n)
          acc[m][n] = __builtin_amdgcn_mfma_f32_16x16x32_bf16(af[m], bb[n], acc[m][n], 0, 0, 0);
    }
    asm volatile("s_waitcnt vmcnt(0)" ::: "memory");
    __syncthreads();
    cur ^= 1;
  }
#pragma unroll
  for (int m = 0; m < 2; ++m) {
#pragma unroll
    for (int n = 0; n < 4; ++n) {
      int col = n0 + wc * 64 + n * 16 + l15;
#pragma unroll
      for (int j = 0; j < 4; ++j) {
        int row = m0 + wr * 32 + m * 16 + lhi * 4 + j;
        if (OUT_BF16)
          ((unsigned short*)Cout)[(size_t)row * N + col] = f2bf(acc[m][n][j]);
        else
          ((float*)Cout)[(size_t)row * N + col] = acc[m][n][j];
      }
    }
  }
}

// ---------------- sparse FFN v9: split-F, v3 skeleton ----------------------
// Grid 1040: block = (tile = bid>>1, fh = bid&1). Each block: 8 ft-iters
// (ft = fh*8+it) over its F-half, v3's LDS-dbuf staging. fh0 -> ybufA
// (+gate*b2), fh1 -> ybufB. Partials summed in GEMM2's gather.
__global__ __launch_bounds__(256, 2) void ffn_sparse_v9(
    const unsigned short* __restrict__ hbf,   // [32768][128]
    const int* __restrict__ ctrl,
    const int* __restrict__ perm,             // [NSLOT]
    const float* __restrict__ gateb,          // [NSLOT]
    const unsigned short* __restrict__ W1F,   // [e][16][8][64][8]
    const float* __restrict__ b1,             // [8][512]
    const unsigned short* __restrict__ W2F,   // [e][16][2][4][64][8]
    const float* __restrict__ b2,             // [8][128]
    unsigned short* __restrict__ ybufA,       // [NSLOT][128]
    unsigned short* __restrict__ ybufB) {     // [NSLOT][128]
  const int tile = blockIdx.x >> 1, fh = blockIdx.x & 1;
  int e = -1;
  {
    int accT = 0;
#pragma unroll
    for (int i = 0; i < 8; ++i) {
      int tiles = (ctrl[CTRL_CNT + i] + 127) >> 7;
      if (e < 0 && tile < accT + tiles) e = i;
      accT += tiles;
    }
  }
  if (e < 0) return;
  __shared__ unsigned short W1c[2][4096];
  __shared__ unsigned short W2c[2][4096];
  __shared__ float b1_s[512];
  __shared__ float b2_s[128];
  const int tid = threadIdx.x, l = tid & 63, w = tid >> 6;
  const int l31 = l & 31, lh = l >> 5;
  const int slot = tile * 128 + w * 32 + l31;
  const int prow = perm[slot];
  const float gate = gateb[slot];

  // h B-fragments: col=tok(l31), k=hd = kk*16 + lh*8 + j  (held all kernel)
  bf16x8 hreg[8];
  const unsigned short* hsrc = hbf + (size_t)prow * 128 + lh * 8;
#pragma unroll
  for (int kk = 0; kk < 8; ++kk)
    hreg[kk] = *(const bf16x8*)(hsrc + kk * 16);

  if (tid < 128) ((float4*)b1_s)[tid] = ((const float4*)(b1 + e * 512))[tid];
  if (tid < 32)  ((float4*)b2_s)[tid] = ((const float4*)(b2 + e * 128))[tid];

  const unsigned short* W1e = W1F + (size_t)e * 65536;
  const unsigned short* W2e = W2F + (size_t)e * 65536;
  auto stage = [&](int buf, int ft) {
#pragma unroll
    for (int r = 0; r < 2; ++r) {
      gload_lds16(W1e + (size_t)ft * 4096 + (size_t)(r * 256 + tid) * 8,
                  &W1c[buf][r * 2048 + w * 512]);
      gload_lds16(W2e + (size_t)ft * 4096 + (size_t)(r * 256 + tid) * 8,
                  &W2c[buf][r * 2048 + w * 512]);
    }
  };

  const int ftbase = fh * 8;
  stage(0, ftbase);
  asm volatile("s_waitcnt vmcnt(0)" ::: "memory");
  __syncthreads();

  f32x16 yacc[4] = {};
  int cur = 0;
  for (int it = 0; it < 8; ++it) {
    const int ft = ftbase + it;
    if (it < 7) stage(cur ^ 1, ft + 1);
    // aacc init = b1 (rows: f = ft*32 + (reg&3) + 8*(reg>>2) + 4*lh)
    const float4* b14 = (const float4*)b1_s;
    float4 q0 = b14[ft * 8 + lh];
    float4 q1 = b14[ft * 8 + lh + 2];
    float4 q2 = b14[ft * 8 + lh + 4];
    float4 q3 = b14[ft * 8 + lh + 6];
    f32x16 aacc = {q0.x, q0.y, q0.z, q0.w, q1.x, q1.y, q1.z, q1.w,
                   q2.x, q2.y, q2.z, q2.w, q3.x, q3.y, q3.z, q3.w};
#pragma unroll
    for (int kk = 0; kk < 8; ++kk) {
      bf16x8 a1 = *(const bf16x8*)&W1c[cur][(kk * 64 + l) * 8];
      aacc = __builtin_amdgcn_mfma_f32_32x32x16_bf16(a1, hreg[kk], aacc, 0, 0, 0);
    }
    // gelu(tanh) * gate, in-register
    float ge[16];
#pragma unroll
    for (int r = 0; r < 16; ++r) {
      float v = aacc[r];
      float s2 = v * v;
      float q = fmaf(0.1029432f, s2, 2.3022078f);
      float E = exp2f(v * q);
      float rc = __builtin_amdgcn_rcpf(E + 1.f);
      ge[r] = fmaf(-v, rc, v) * gate;
    }
    // pack pairs -> bf16 words; swap halves to form B-frags (k = f)
    unsigned pk[8];
#pragma unroll
    for (int p = 0; p < 8; ++p) {
      unsigned r;
      asm("v_cvt_pk_bf16_f32 %0, %1, %2" : "=v"(r) : "v"(ge[2 * p]), "v"(ge[2 * p + 1]));
      pk[p] = r;
    }
    asm volatile("v_permlane32_swap_b32 %0, %1" : "+v"(pk[0]), "+v"(pk[2]));
    asm volatile("v_permlane32_swap_b32 %0, %1" : "+v"(pk[1]), "+v"(pk[3]));
    asm volatile("v_permlane32_swap_b32 %0, %1" : "+v"(pk[4]), "+v"(pk[6]));
    asm volatile("v_permlane32_swap_b32 %0, %1" : "+v"(pk[5]), "+v"(pk[7]));
    typedef __attribute__((ext_vector_type(4))) unsigned u32x4;
    u32x4 f0 = {pk[0], pk[1], pk[2], pk[3]};
    u32x4 f1 = {pk[4], pk[5], pk[6], pk[7]};
    bf16x8 act0 = __builtin_bit_cast(bf16x8, f0);
    bf16x8 act1 = __builtin_bit_cast(bf16x8, f1);
    // phase 2: yacc[ht] += W2frag @ act
#pragma unroll
    for (int ht = 0; ht < 4; ++ht) {
      bf16x8 a20 = *(const bf16x8*)&W2c[cur][(ht * 64 + l) * 8];
      yacc[ht] = __builtin_amdgcn_mfma_f32_32x32x16_bf16(a20, act0, yacc[ht], 0, 0, 0);
      bf16x8 a21 = *(const bf16x8*)&W2c[cur][((4 + ht) * 64 + l) * 8];
      yacc[ht] = __builtin_amdgcn_mfma_f32_32x32x16_bf16(a21, act1, yacc[ht], 0, 0, 0);
    }
    asm volatile("s_waitcnt vmcnt(0)" ::: "memory");
    __syncthreads();
    cur ^= 1;
  }
  // epilogue: fh0 -> ybufA (+gate*b2); fh1 -> ybufB
  unsigned short* yout = fh ? ybufB : ybufA;
#pragma unroll
  for (int ht = 0; ht < 4; ++ht) {
#pragma unroll
    for (int rp = 0; rp < 8; ++rp) {
      int fr = ((2 * rp) & 3) + 8 * (rp >> 1) + 4 * lh;
      int hd = ht * 32 + fr;
      float v0 = yacc[ht][2 * rp];
      float v1 = yacc[ht][2 * rp + 1];
      if (fh == 0) {
        float2 bb2 = *(const float2*)&b2_s[hd];
        v0 = fmaf(gate, bb2.x, v0);
        v1 = fmaf(gate, bb2.y, v1);
      }
      unsigned pw;
      asm("v_cvt_pk_bf16_f32 %0, %1, %2" : "=v"(pw) : "v"(v0), "v"(v1));
      *(unsigned*)(yout + (size_t)slot * 128 + hd) = pw;
    }
  }
}

// ---------------------------------------------------------------------------
extern "C" void kernel_launch(void* const* d_in, const int* in_sizes, int n_in,
                              void* d_out, int out_size, void* d_ws, size_t ws_size,
                              hipStream_t stream) {
  const float* x       = (const float*)d_in[0];
  const float* W_mh    = (const float*)d_in[1];
  const float* b_mh    = (const float*)d_in[2];
  const float* W_merge = (const float*)d_in[3];
  const float* b_merge = (const float*)d_in[4];
  const float* W_rout  = (const float*)d_in[5];
  const float* W1      = (const float*)d_in[6];
  const float* b1      = (const float*)d_in[7];
  const float* W2      = (const float*)d_in[8];
  const float* b2      = (const float*)d_in[9];
  float* out = (float*)d_out;

  char* ws = (char*)d_ws;
  size_t off = 0;
  auto alloc = [&](size_t bytes) {
    void* p = ws + off;
    off = (off + bytes + 255) & ~(size_t)255;
    return p;
  };
  unsigned short* x_bf  = (unsigned short*)alloc((size_t)4096 * 1024 * 2);
  unsigned short* Wmh_t = (unsigned short*)alloc((size_t)1024 * 1024 * 2);
  unsigned short* Wmg_t = (unsigned short*)alloc((size_t)1024 * 1024 * 2);
  unsigned short* W1F   = (unsigned short*)alloc((size_t)8 * 512 * 128 * 2);
  unsigned short* W2F   = (unsigned short*)alloc((size_t)8 * 512 * 128 * 2);
  unsigned short* h_bf  = (unsigned short*)alloc((size_t)4096 * 1024 * 2);
  unsigned short* ybufA = (unsigned short*)alloc((size_t)NSLOT * 128 * 2);
  unsigned short* ybufB = (unsigned short*)alloc((size_t)NSLOT * 128 * 2);
  float* Wc             = (float*)alloc((size_t)1025 * 64 * 4);
  float* part           = (float*)alloc((size_t)8 * 4096 * 64 * 4);
  int*   ctrl           = (int*)alloc(4096);
  int*   tok_e          = (int*)alloc((size_t)32768 * 2 * 4);
  float* tok_g          = (float*)alloc((size_t)32768 * 2 * 4);
  int*   tok_slot       = (int*)alloc((size_t)32768 * 2 * 4);
  int*   perm           = (int*)alloc((size_t)NSLOT * 4);
  float* gateb          = (float*)alloc((size_t)NSLOT * 4);

  prep_all<<<2817, 256, 0, stream>>>(W_mh, Wmh_t, W_merge, Wmg_t,
                                     W1, W2, W1F, W2F, b_mh, W_rout, Wc, ctrl);
  router_partial<<<dim3(8, 128), 256, 0, stream>>>(x, Wc, part, x_bf, perm, gateb);
  router_reduce<<<128, 256, 0, stream>>>(part, Wc, tok_e, tok_g, ctrl);
  assign_kernel<<<128, 256, 0, stream>>>(tok_e, tok_g, ctrl, perm, gateb, tok_slot);
  gemm_bt<1, 0><<<dim3(32, 8), 512, 0, stream>>>(x_bf, Wmh_t, b_mh, (void*)h_bf,
                                                 4096, 1024, 1024, nullptr, nullptr, nullptr);
  ffn_sparse_v9<<<NTILE_MAX * 2, 256, 0, stream>>>(h_bf, ctrl, perm, gateb,
                                                   W1F, b1, W2F, b2, ybufA, ybufB);
  gemm_bt<0, 1><<<dim3(32, 8), 512, 0, stream>>>(nullptr, Wmg_t, b_merge, (void*)out,
                                                 4096, 1024, 1024, ybufA, ybufB, tok_slot);
}

// Round 13
// 139.082 us; speedup vs baseline: 1.1117x; 1.1117x over previous
//
#include <hip/hip_runtime.h>

// ---------------------------------------------------------------------------
// MH-MoE, top-2 sparse dispatch, in-register expert FFN.
// B=2 S=2048 H=1024 NH=8 HD=128 T=16384 (32768 tokens) E=8 K=2 F=512
// R13: R11 baseline (best measured: 139.3us) with FFN v10 = v3 body +
// triple-buffered weight staging + counted s_waitcnt vmcnt(4) + raw s_barrier
// (clean count window: b1/b2 in LDS, loop VMEM = staging loads only).
// Split-K router, 128x128 8-wave GEMMs, fused top-2 combine in GEMM2.
// ---------------------------------------------------------------------------

typedef __attribute__((ext_vector_type(8))) short bf16x8;
typedef __attribute__((ext_vector_type(4))) float f32x4;
typedef __attribute__((ext_vector_type(16))) float f32x16;
typedef __attribute__((ext_vector_type(4))) unsigned short u16x4;

constexpr int NSLOT = 66560;      // 520 tiles * 128 slots
constexpr int NTILE_MAX = 520;
#define CTRL_CNT 0
#define CTRL_CUR 8

__device__ __forceinline__ unsigned short f2bf(float x) {
  unsigned int u = __float_as_uint(x);
  return (unsigned short)((u + 0x7FFFu + ((u >> 16) & 1u)) >> 16);
}
__device__ __forceinline__ float bf2f(unsigned short u) {
  return __uint_as_float(((unsigned int)u) << 16);
}
__device__ __forceinline__ void gload_lds16(const void* g, void* l) {
  __builtin_amdgcn_global_load_lds(
      (const __attribute__((address_space(1))) unsigned int*)g,
      (__attribute__((address_space(3))) unsigned int*)l, 16, 0, 0);
}

// ---------------- prep: transposes + W1F/W2F + Wcomb ----------------
__global__ __launch_bounds__(256) void prep_all(
    const float* __restrict__ Wmh, unsigned short* __restrict__ Wmh_t,
    const float* __restrict__ Wmg, unsigned short* __restrict__ Wmg_t,
    const float* __restrict__ W1, const float* __restrict__ W2,
    unsigned short* __restrict__ W1F, unsigned short* __restrict__ W2F,
    const float* __restrict__ bmh, const float* __restrict__ Wr,
    float* __restrict__ Wc, int* __restrict__ ctrl) {
  __shared__ float smem[2048];
  const int bid = blockIdx.x, tid = threadIdx.x;
  if (bid < 2048) {
    if (bid == 0 && tid < 16) ctrl[tid] = 0;
    const float* src = (bid < 1024) ? Wmh : Wmg;
    unsigned short* dst = (bid < 1024) ? Wmh_t : Wmg_t;
    const int bb = bid & 1023;
    const int c0 = (bb & 31) * 32, r0 = (bb >> 5) * 32;
    const int tx = tid & 31, ty = tid >> 5;
    float (*tile)[33] = (float(*)[33])smem;
    for (int i = ty; i < 32; i += 8)
      tile[i][tx] = src[(size_t)(r0 + i) * 1024 + c0 + tx];
    __syncthreads();
    for (int i = ty; i < 32; i += 8)
      dst[(size_t)(c0 + i) * 1024 + r0 + tx] = f2bf(tile[tx][i]);
  } else if (bid < 2560) {
    // W1F[e][ft16][kk8][l64][j8], W2F[e][ft16][s2][ht4][l64][j8]
    const int jid = (bid - 2048) * 4 + (tid >> 6);   // 0..2047
    const int l = tid & 63;
    const int is2 = jid >= 1024;
    const int bj = is2 ? jid - 1024 : jid;
    const float* src;
    int C;
    if (!is2) {
      int kk = bj & 7, ft = (bj >> 3) & 15, e = bj >> 7;
      src = W1 + (size_t)e * 65536 + (size_t)(kk * 16) * 512 + ft * 32;
      C = 512;
    } else {
      int sht = bj & 7, ft = (bj >> 3) & 15, e = bj >> 7;
      src = W2 + (size_t)e * 65536 + (size_t)(ft * 32 + (sht >> 2) * 16) * 128 + (sht & 3) * 32;
      C = 128;
    }
    float* tile = smem + (tid >> 6) * 512;   // [16][32]
#pragma unroll
    for (int r = 0; r < 8; ++r) {
      int i = l + 64 * r;
      tile[(i >> 5) * 32 + (i & 31)] = src[(size_t)(i >> 5) * C + (i & 31)];
    }
    __syncthreads();
    int l31 = l & 31, lh = l >> 5;
    bf16x8 v;
#pragma unroll
    for (int j = 0; j < 8; ++j) v[j] = (short)f2bf(tile[(lh * 8 + j) * 32 + l31]);
    unsigned short* dst = is2 ? W2F : W1F;
    *(bf16x8*)(dst + ((size_t)bj * 64 + l) * 8) = v;
  } else {
    const int r = (bid - 2560) * 4 + (tid >> 6);
    if (r > 1024) return;
    const int l = tid & 63;
    const float* src = (r < 1024) ? (Wmh + (size_t)r * 1024) : bmh;
    int nh = l >> 3, e = l & 7;
    float acc = 0.f;
    for (int d = 0; d < 128; ++d) acc = fmaf(src[nh * 128 + d], Wr[d * 8 + e], acc);
    Wc[(size_t)r * 64 + l] = acc;
  }
}

// ---------------- router pass 1: split-K partial logits + x_bf -------------
__global__ __launch_bounds__(256) void router_partial(
    const float* __restrict__ x, const float* __restrict__ Wc,
    float* __restrict__ part, unsigned short* __restrict__ x_bf,
    int* __restrict__ perm, float* __restrict__ gateb) {
  const int tid = threadIdx.x;
  const int kc = blockIdx.x, rb = blockIdx.y;
  int gi = (rb * 8 + kc) * 256 + tid;
  if (gi < NSLOT) { perm[gi] = 0; gateb[gi] = 0.f; }

  __shared__ float xs[32][128];    // 16 KB
  __shared__ float wcs[128][64];   // 32 KB
  const int r0 = rb * 32, k0 = kc * 128;

  for (int f = tid; f < 1024; f += 256) {
    int row = f >> 5, j4 = (f & 31) * 4;
    float4 v = *(const float4*)&x[(size_t)(r0 + row) * 1024 + k0 + j4];
    *(float4*)&xs[row][j4] = v;
    u16x4 o;
    o.x = f2bf(v.x); o.y = f2bf(v.y); o.z = f2bf(v.z); o.w = f2bf(v.w);
    *(u16x4*)&x_bf[(size_t)(r0 + row) * 1024 + k0 + j4] = o;
  }
  {
    const float4* src = (const float4*)(Wc + (size_t)k0 * 64);
    float4* dst = (float4*)&wcs[0][0];
    for (int f = tid; f < 2048; f += 256) dst[f] = src[f];
  }
  __syncthreads();

  const int col = tid & 63, rg = tid >> 6;
  float a[8] = {0.f, 0.f, 0.f, 0.f, 0.f, 0.f, 0.f, 0.f};
  for (int k4 = 0; k4 < 32; ++k4) {
    float4 xv[8];
#pragma unroll
    for (int i = 0; i < 8; ++i)
      xv[i] = *(const float4*)&xs[rg * 8 + i][k4 * 4];
#pragma unroll
    for (int u = 0; u < 4; ++u) {
      float wv = wcs[k4 * 4 + u][col];
#pragma unroll
      for (int i = 0; i < 8; ++i)
        a[i] = fmaf((&xv[i].x)[u], wv, a[i]);
    }
  }
#pragma unroll
  for (int i = 0; i < 8; ++i)
    part[(size_t)kc * 262144 + (size_t)(r0 + rg * 8 + i) * 64 + col] = a[i];
}

// ---------------- router pass 2: fixed-order reduce + top-2 + counts -------
__global__ __launch_bounds__(256) void router_reduce(
    const float* __restrict__ part, const float* __restrict__ Wc,
    int* __restrict__ tok_e, float* __restrict__ tok_g,
    int* __restrict__ ctrl) {
  __shared__ float lg[32][64];
  __shared__ int lcnt[8];
  const int tid = threadIdx.x;
  if (tid < 8) lcnt[tid] = 0;
  const int r0 = blockIdx.x * 32;
  const int col = tid & 63, rg = tid >> 6;
#pragma unroll
  for (int i = 0; i < 8; ++i) {
    size_t base = (size_t)(r0 + rg * 8 + i) * 64 + col;
    float s = Wc[65536 + col];
#pragma unroll
    for (int kc = 0; kc < 8; ++kc) s += part[(size_t)kc * 262144 + base];
    lg[rg * 8 + i][col] = s;
  }
  __syncthreads();
  {
    int row = tid >> 3, nh = tid & 7;
    float l[8];
#pragma unroll
    for (int e = 0; e < 8; ++e) l[e] = lg[row][nh * 8 + e];
    int i1 = 0; float v1 = l[0];
#pragma unroll
    for (int e = 1; e < 8; ++e) if (l[e] > v1) { v1 = l[e]; i1 = e; }
    int i2 = -1; float v2 = -1e30f;
#pragma unroll
    for (int e = 0; e < 8; ++e) if (e != i1 && l[e] > v2) { v2 = l[e]; i2 = e; }
    float g1 = 1.f / (1.f + __expf(v2 - v1));
    float g2 = 1.f - g1;
    size_t t = (size_t)(r0 + row) * 8 + nh;
    tok_e[t * 2] = i1; tok_e[t * 2 + 1] = i2;
    tok_g[t * 2] = g1; tok_g[t * 2 + 1] = g2;
    atomicAdd(&lcnt[i1], 1);
    atomicAdd(&lcnt[i2], 1);
  }
  __syncthreads();
  if (tid < 8 && lcnt[tid])
    atomicAdd(&ctrl[CTRL_CNT + tid], lcnt[tid]);
}

// ---------------- assign (unchanged) ----------------
__global__ __launch_bounds__(256) void assign_kernel(
    const int* __restrict__ tok_e, const float* __restrict__ tok_g,
    int* __restrict__ ctrl, int* __restrict__ perm,
    float* __restrict__ gateb, int* __restrict__ tok_slot) {
  __shared__ int lcnt[8], lbase[8];
  if (threadIdx.x < 8) lcnt[threadIdx.x] = 0;
  __syncthreads();
  int t = blockIdx.x * 256 + threadIdx.x;
  int e0 = tok_e[t * 2], e1 = tok_e[t * 2 + 1];
  int p0 = atomicAdd(&lcnt[e0], 1);
  int p1 = atomicAdd(&lcnt[e1], 1);
  __syncthreads();
  if (threadIdx.x < 8)
    lbase[threadIdx.x] = atomicAdd(&ctrl[CTRL_CUR + threadIdx.x], lcnt[threadIdx.x]);
  __syncthreads();
  int off0 = 0, off1 = 0, acc = 0;
#pragma unroll
  for (int i = 0; i < 8; ++i) {
    int cnt = ctrl[CTRL_CNT + i];
    if (i == e0) off0 = acc;
    if (i == e1) off1 = acc;
    acc += (cnt + 127) & ~127;
  }
  int s0 = off0 + lbase[e0] + p0;
  int s1 = off1 + lbase[e1] + p1;
  perm[s0] = t; perm[s1] = t;
  gateb[s0] = tok_g[t * 2]; gateb[s1] = tok_g[t * 2 + 1];
  tok_slot[t * 2] = s0; tok_slot[t * 2 + 1] = s1;
}

// ---------------- GEMM: C[M][N] = A[M][K](bf16) @ Bt[N][K](bf16)^T + bias --
// 128x128 tile, BK=64, 512 threads = 8 waves, 64KB LDS dbuf.
// A_GATHER=1: A row r, col k = ybuf[s0][k%128]+ybuf[s1][k%128], tok=r*8+k/128.
template <int OUT_BF16, int A_GATHER>
__global__ __launch_bounds__(512, 4) void gemm_bt(
    const unsigned short* __restrict__ A, const unsigned short* __restrict__ Bt,
    const float* __restrict__ bias, void* __restrict__ Cout,
    int M, int N, int K,
    const unsigned short* __restrict__ ybuf, const int* __restrict__ tok_slot) {
  __shared__ __align__(16) unsigned short As[2][128 * 64];
  __shared__ __align__(16) unsigned short Bs[2][128 * 64];
  const int tid = threadIdx.x, lane = tid & 63, w = tid >> 6;
  const int wr = w >> 1, wc = w & 1;
  const int m0 = blockIdx.x * 128, n0 = blockIdx.y * 128;
  const int l15 = lane & 15, lhi = lane >> 4;

  f32x4 acc[2][4];
#pragma unroll
  for (int n = 0; n < 4; ++n) {
    float bv = bias[n0 + wc * 64 + n * 16 + l15];
#pragma unroll
    for (int m = 0; m < 2; ++m) acc[m][n] = (f32x4){bv, bv, bv, bv};
  }

  const int rowi = tid >> 3;       // 0..63
  const int segi = (tid & 7) * 8;  // k offset
  const int NT = K >> 6;

  auto stage = [&](int buf, int kt) {
    const int k0 = kt * 64;
    if constexpr (A_GATHER) {
#pragma unroll
      for (int r = 0; r < 2; ++r) {
        int arow = m0 + r * 64 + rowi;
        int k = k0 + segi;
        int tok = arow * 8 + (k >> 7);
        int hd = k & 127;
        int s0 = tok_slot[tok * 2], s1 = tok_slot[tok * 2 + 1];
        bf16x8 va = *(const bf16x8*)(ybuf + (size_t)s0 * 128 + hd);
        bf16x8 vb = *(const bf16x8*)(ybuf + (size_t)s1 * 128 + hd);
        bf16x8 vs;
#pragma unroll
        for (int j = 0; j < 8; ++j)
          vs[j] = (short)f2bf(bf2f((unsigned short)va[j]) + bf2f((unsigned short)vb[j]));
        *(bf16x8*)&As[buf][r * 4096 + tid * 8] = vs;
      }
    } else {
#pragma unroll
      for (int r = 0; r < 2; ++r)
        gload_lds16(A + (size_t)(m0 + r * 64 + rowi) * K + k0 + segi,
                    &As[buf][r * 4096 + w * 512]);
    }
#pragma unroll
    for (int r = 0; r < 2; ++r)
      gload_lds16(Bt + (size_t)(n0 + r * 64 + rowi) * K + k0 + segi,
                  &Bs[buf][r * 4096 + w * 512]);
  };

  stage(0, 0);
  asm volatile("s_waitcnt vmcnt(0)" ::: "memory");
  __syncthreads();
  int cur = 0;
  for (int t = 0; t < NT; ++t) {
    if (t + 1 < NT) stage(cur ^ 1, t + 1);
#pragma unroll
    for (int ks = 0; ks < 64; ks += 32) {
      bf16x8 af[2], bb[4];
#pragma unroll
      for (int m = 0; m < 2; ++m)
        af[m] = *(const bf16x8*)&As[cur][(wr * 32 + m * 16 + l15) * 64 + ks + lhi * 8];
#pragma unroll
      for (int n = 0; n < 4; ++n)
        bb[n] = *(const bf16x8*)&Bs[cur][(wc * 64 + n * 16 + l15) * 64 + ks + lhi * 8];
#pragma unroll
      for (int m = 0; m < 2; ++m)
#pragma unroll
        for (int n = 0; n < 4; ++n)
          acc[m][n] = __builtin_amdgcn_mfma_f32_16x16x32_bf16(af[m], bb[n], acc[m][n], 0, 0, 0);
    }
    asm volatile("s_waitcnt vmcnt(0)" ::: "memory");
    __syncthreads();
    cur ^= 1;
  }
#pragma unroll
  for (int m = 0; m < 2; ++m) {
#pragma unroll
    for (int n = 0; n < 4; ++n) {
      int col = n0 + wc * 64 + n * 16 + l15;
#pragma unroll
      for (int j = 0; j < 4; ++j) {
        int row = m0 + wr * 32 + m * 16 + lhi * 4 + j;
        if (OUT_BF16)
          ((unsigned short*)Cout)[(size_t)row * N + col] = f2bf(acc[m][n][j]);
        else
          ((float*)Cout)[(size_t)row * N + col] = acc[m][n][j];
      }
    }
  }
}

// ---------------- sparse FFN v10: v3 body + 3-buf counted vmcnt ------------
// Block: 128 slots, 4 waves, 16 iters. Iter top: issue stage(it+2) (4 loads).
// End of iter: s_waitcnt vmcnt(4) (drains stage(it+1) only; window clean —
// loop VMEM = staging loads only, b1/b2 in LDS) + raw s_barrier.
__global__ __launch_bounds__(256, 3) void ffn_sparse_v10(
    const unsigned short* __restrict__ hbf,   // [32768][128]
    const int* __restrict__ ctrl,
    const int* __restrict__ perm,             // [NSLOT]
    const float* __restrict__ gateb,          // [NSLOT]
    const unsigned short* __restrict__ W1F,   // [e][16][8][64][8]
    const float* __restrict__ b1,             // [8][512]
    const unsigned short* __restrict__ W2F,   // [e][16][2][4][64][8]
    const float* __restrict__ b2,             // [8][128]
    unsigned short* __restrict__ ybuf) {      // [NSLOT][128]
  int e = -1;
  {
    int accT = 0;
#pragma unroll
    for (int i = 0; i < 8; ++i) {
      int tiles = (ctrl[CTRL_CNT + i] + 127) >> 7;
      if (e < 0 && (int)blockIdx.x < accT + tiles) e = i;
      accT += tiles;
    }
  }
  if (e < 0) return;
  __shared__ __align__(16) unsigned short W1c[3][4096];
  __shared__ __align__(16) unsigned short W2c[3][4096];
  __shared__ float b1_s[512];
  __shared__ float b2_s[128];
  const int tid = threadIdx.x, l = tid & 63, w = tid >> 6;
  const int l31 = l & 31, lh = l >> 5;
  const int slot = blockIdx.x * 128 + w * 32 + l31;
  const int prow = perm[slot];
  const float gate = gateb[slot];

  // h B-fragments: col=tok(l31), k=hd = kk*16 + lh*8 + j  (held all kernel)
  bf16x8 hreg[8];
  const unsigned short* hsrc = hbf + (size_t)prow * 128 + lh * 8;
#pragma unroll
  for (int kk = 0; kk < 8; ++kk)
    hreg[kk] = *(const bf16x8*)(hsrc + kk * 16);

  if (tid < 128) ((float4*)b1_s)[tid] = ((const float4*)(b1 + e * 512))[tid];
  if (tid < 32)  ((float4*)b2_s)[tid] = ((const float4*)(b2 + e * 128))[tid];

  const unsigned short* W1e = W1F + (size_t)e * 65536;
  const unsigned short* W2e = W2F + (size_t)e * 65536;
  auto stage = [&](int buf, int ft) {
#pragma unroll
    for (int r = 0; r < 2; ++r) {
      gload_lds16(W1e + (size_t)ft * 4096 + (size_t)(r * 256 + tid) * 8,
                  &W1c[buf][r * 2048 + w * 512]);
      gload_lds16(W2e + (size_t)ft * 4096 + (size_t)(r * 256 + tid) * 8,
                  &W2c[buf][r * 2048 + w * 512]);
    }
  };

  // prologue: 2 tiles in flight; drain only the first
  stage(0, 0);
  stage(1, 1);
  asm volatile("s_waitcnt vmcnt(4)" ::: "memory");
  __builtin_amdgcn_s_barrier();

  f32x16 yacc[4] = {};
  for (int ft = 0; ft < 16; ++ft) {
    const int buf = ft % 3;
    if (ft + 2 < 16) stage((ft + 2) % 3, ft + 2);
    // aacc init = b1 (rows: f = ft*32 + (reg&3) + 8*(reg>>2) + 4*lh)
    const float4* b14 = (const float4*)b1_s;
    float4 q0 = b14[ft * 8 + lh];
    float4 q1 = b14[ft * 8 + lh + 2];
    float4 q2 = b14[ft * 8 + lh + 4];
    float4 q3 = b14[ft * 8 + lh + 6];
    f32x16 aacc = {q0.x, q0.y, q0.z, q0.w, q1.x, q1.y, q1.z, q1.w,
                   q2.x, q2.y, q2.z, q2.w, q3.x, q3.y, q3.z, q3.w};
#pragma unroll
    for (int kk = 0; kk < 8; ++kk) {
      bf16x8 a1 = *(const bf16x8*)&W1c[buf][(kk * 64 + l) * 8];
      aacc = __builtin_amdgcn_mfma_f32_32x32x16_bf16(a1, hreg[kk], aacc, 0, 0, 0);
    }
    // gelu(tanh) * gate, in-register
    float ge[16];
#pragma unroll
    for (int r = 0; r < 16; ++r) {
      float v = aacc[r];
      float s2 = v * v;
      float q = fmaf(0.1029432f, s2, 2.3022078f);
      float E = exp2f(v * q);
      float rc = __builtin_amdgcn_rcpf(E + 1.f);
      ge[r] = fmaf(-v, rc, v) * gate;
    }
    // pack pairs -> bf16 words; swap halves to form B-frags (k = f)
    unsigned pk[8];
#pragma unroll
    for (int p = 0; p < 8; ++p) {
      unsigned r;
      asm("v_cvt_pk_bf16_f32 %0, %1, %2" : "=v"(r) : "v"(ge[2 * p]), "v"(ge[2 * p + 1]));
      pk[p] = r;
    }
    asm volatile("v_permlane32_swap_b32 %0, %1" : "+v"(pk[0]), "+v"(pk[2]));
    asm volatile("v_permlane32_swap_b32 %0, %1" : "+v"(pk[1]), "+v"(pk[3]));
    asm volatile("v_permlane32_swap_b32 %0, %1" : "+v"(pk[4]), "+v"(pk[6]));
    asm volatile("v_permlane32_swap_b32 %0, %1" : "+v"(pk[5]), "+v"(pk[7]));
    typedef __attribute__((ext_vector_type(4))) unsigned u32x4;
    u32x4 f0 = {pk[0], pk[1], pk[2], pk[3]};
    u32x4 f1 = {pk[4], pk[5], pk[6], pk[7]};
    bf16x8 act0 = __builtin_bit_cast(bf16x8, f0);
    bf16x8 act1 = __builtin_bit_cast(bf16x8, f1);
    // phase 2: yacc[ht] += W2frag @ act
#pragma unroll
    for (int ht = 0; ht < 4; ++ht) {
      bf16x8 a20 = *(const bf16x8*)&W2c[buf][(ht * 64 + l) * 8];
      yacc[ht] = __builtin_amdgcn_mfma_f32_32x32x16_bf16(a20, act0, yacc[ht], 0, 0, 0);
      bf16x8 a21 = *(const bf16x8*)&W2c[buf][((4 + ht) * 64 + l) * 8];
      yacc[ht] = __builtin_amdgcn_mfma_f32_32x32x16_bf16(a21, act1, yacc[ht], 0, 0, 0);
    }
    // counted wait: drain stage(ft+1) only; never 0 until the tail
    if (ft < 15) {
      if (ft + 2 < 16) {
        asm volatile("s_waitcnt vmcnt(4)" ::: "memory");
      } else {
        asm volatile("s_waitcnt vmcnt(0)" ::: "memory");
      }
      __builtin_amdgcn_s_barrier();
    }
  }
  // epilogue: y + gate*b2 -> bf16 pairs -> 4B stores (col = own token)
#pragma unroll
  for (int ht = 0; ht < 4; ++ht) {
#pragma unroll
    for (int rp = 0; rp < 8; ++rp) {
      int fr = ((2 * rp) & 3) + 8 * (rp >> 1) + 4 * lh;
      int hd = ht * 32 + fr;
      float2 bb2 = *(const float2*)&b2_s[hd];
      float v0 = fmaf(gate, bb2.x, yacc[ht][2 * rp]);
      float v1 = fmaf(gate, bb2.y, yacc[ht][2 * rp + 1]);
      unsigned pw;
      asm("v_cvt_pk_bf16_f32 %0, %1, %2" : "=v"(pw) : "v"(v0), "v"(v1));
      *(unsigned*)(ybuf + (size_t)slot * 128 + hd) = pw;
    }
  }
}

// ---------------------------------------------------------------------------
extern "C" void kernel_launch(void* const* d_in, const int* in_sizes, int n_in,
                              void* d_out, int out_size, void* d_ws, size_t ws_size,
                              hipStream_t stream) {
  const float* x       = (const float*)d_in[0];
  const float* W_mh    = (const float*)d_in[1];
  const float* b_mh    = (const float*)d_in[2];
  const float* W_merge = (const float*)d_in[3];
  const float* b_merge = (const float*)d_in[4];
  const float* W_rout  = (const float*)d_in[5];
  const float* W1      = (const float*)d_in[6];
  const float* b1      = (const float*)d_in[7];
  const float* W2      = (const float*)d_in[8];
  const float* b2      = (const float*)d_in[9];
  float* out = (float*)d_out;

  char* ws = (char*)d_ws;
  size_t off = 0;
  auto alloc = [&](size_t bytes) {
    void* p = ws + off;
    off = (off + bytes + 255) & ~(size_t)255;
    return p;
  };
  unsigned short* x_bf  = (unsigned short*)alloc((size_t)4096 * 1024 * 2);
  unsigned short* Wmh_t = (unsigned short*)alloc((size_t)1024 * 1024 * 2);
  unsigned short* Wmg_t = (unsigned short*)alloc((size_t)1024 * 1024 * 2);
  unsigned short* W1F   = (unsigned short*)alloc((size_t)8 * 512 * 128 * 2);
  unsigned short* W2F   = (unsigned short*)alloc((size_t)8 * 512 * 128 * 2);
  unsigned short* h_bf  = (unsigned short*)alloc((size_t)4096 * 1024 * 2);
  unsigned short* ybuf  = (unsigned short*)alloc((size_t)NSLOT * 128 * 2);
  float* Wc             = (float*)alloc((size_t)1025 * 64 * 4);
  float* part           = (float*)alloc((size_t)8 * 4096 * 64 * 4);
  int*   ctrl           = (int*)alloc(4096);
  int*   tok_e          = (int*)alloc((size_t)32768 * 2 * 4);
  float* tok_g          = (float*)alloc((size_t)32768 * 2 * 4);
  int*   tok_slot       = (int*)alloc((size_t)32768 * 2 * 4);
  int*   perm           = (int*)alloc((size_t)NSLOT * 4);
  float* gateb          = (float*)alloc((size_t)NSLOT * 4);

  prep_all<<<2817, 256, 0, stream>>>(W_mh, Wmh_t, W_merge, Wmg_t,
                                     W1, W2, W1F, W2F, b_mh, W_rout, Wc, ctrl);
  router_partial<<<dim3(8, 128), 256, 0, stream>>>(x, Wc, part, x_bf, perm, gateb);
  router_reduce<<<128, 256, 0, stream>>>(part, Wc, tok_e, tok_g, ctrl);
  assign_kernel<<<128, 256, 0, stream>>>(tok_e, tok_g, ctrl, perm, gateb, tok_slot);
  gemm_bt<1, 0><<<dim3(32, 8), 512, 0, stream>>>(x_bf, Wmh_t, b_mh, (void*)h_bf,
                                                 4096, 1024, 1024, nullptr, nullptr);
  ffn_sparse_v10<<<NTILE_MAX, 256, 0, stream>>>(h_bf, ctrl, perm, gateb, W1F, b1, W2F, b2, ybuf);
  gemm_bt<0, 1><<<dim3(32, 8), 512, 0, stream>>>(nullptr, Wmg_t, b_merge, (void*)out,
                                                 4096, 1024, 1024, ybuf, tok_slot);
}

// Round 14
// 133.875 us; speedup vs baseline: 1.1549x; 1.0389x over previous
//
#include <hip/hip_runtime.h>

// ---------------------------------------------------------------------------
// MH-MoE, top-2 sparse dispatch, in-register expert FFN.
// B=2 S=2048 H=1024 NH=8 HD=128 T=16384 (32768 tokens) E=8 K=2 F=512
// R14: GEMMs retiled 128x64, 8 waves (32x32 wave-tiles), grid 512 = 2
// blocks/CU = 4 waves/SIMD (2x R13). FFN v10 (family ceiling 48.5us),
// split-K router, fused top-2 combine in GEMM2.
// ---------------------------------------------------------------------------

typedef __attribute__((ext_vector_type(8))) short bf16x8;
typedef __attribute__((ext_vector_type(4))) float f32x4;
typedef __attribute__((ext_vector_type(16))) float f32x16;
typedef __attribute__((ext_vector_type(4))) unsigned short u16x4;

constexpr int NSLOT = 66560;      // 520 tiles * 128 slots
constexpr int NTILE_MAX = 520;
#define CTRL_CNT 0
#define CTRL_CUR 8

__device__ __forceinline__ unsigned short f2bf(float x) {
  unsigned int u = __float_as_uint(x);
  return (unsigned short)((u + 0x7FFFu + ((u >> 16) & 1u)) >> 16);
}
__device__ __forceinline__ float bf2f(unsigned short u) {
  return __uint_as_float(((unsigned int)u) << 16);
}
__device__ __forceinline__ void gload_lds16(const void* g, void* l) {
  __builtin_amdgcn_global_load_lds(
      (const __attribute__((address_space(1))) unsigned int*)g,
      (__attribute__((address_space(3))) unsigned int*)l, 16, 0, 0);
}

// ---------------- prep: transposes + W1F/W2F + Wcomb ----------------
__global__ __launch_bounds__(256) void prep_all(
    const float* __restrict__ Wmh, unsigned short* __restrict__ Wmh_t,
    const float* __restrict__ Wmg, unsigned short* __restrict__ Wmg_t,
    const float* __restrict__ W1, const float* __restrict__ W2,
    unsigned short* __restrict__ W1F, unsigned short* __restrict__ W2F,
    const float* __restrict__ bmh, const float* __restrict__ Wr,
    float* __restrict__ Wc, int* __restrict__ ctrl) {
  __shared__ float smem[2048];
  const int bid = blockIdx.x, tid = threadIdx.x;
  if (bid < 2048) {
    if (bid == 0 && tid < 16) ctrl[tid] = 0;
    const float* src = (bid < 1024) ? Wmh : Wmg;
    unsigned short* dst = (bid < 1024) ? Wmh_t : Wmg_t;
    const int bb = bid & 1023;
    const int c0 = (bb & 31) * 32, r0 = (bb >> 5) * 32;
    const int tx = tid & 31, ty = tid >> 5;
    float (*tile)[33] = (float(*)[33])smem;
    for (int i = ty; i < 32; i += 8)
      tile[i][tx] = src[(size_t)(r0 + i) * 1024 + c0 + tx];
    __syncthreads();
    for (int i = ty; i < 32; i += 8)
      dst[(size_t)(c0 + i) * 1024 + r0 + tx] = f2bf(tile[tx][i]);
  } else if (bid < 2560) {
    // W1F[e][ft16][kk8][l64][j8], W2F[e][ft16][s2][ht4][l64][j8]
    const int jid = (bid - 2048) * 4 + (tid >> 6);   // 0..2047
    const int l = tid & 63;
    const int is2 = jid >= 1024;
    const int bj = is2 ? jid - 1024 : jid;
    const float* src;
    int C;
    if (!is2) {
      int kk = bj & 7, ft = (bj >> 3) & 15, e = bj >> 7;
      src = W1 + (size_t)e * 65536 + (size_t)(kk * 16) * 512 + ft * 32;
      C = 512;
    } else {
      int sht = bj & 7, ft = (bj >> 3) & 15, e = bj >> 7;
      src = W2 + (size_t)e * 65536 + (size_t)(ft * 32 + (sht >> 2) * 16) * 128 + (sht & 3) * 32;
      C = 128;
    }
    float* tile = smem + (tid >> 6) * 512;   // [16][32]
#pragma unroll
    for (int r = 0; r < 8; ++r) {
      int i = l + 64 * r;
      tile[(i >> 5) * 32 + (i & 31)] = src[(size_t)(i >> 5) * C + (i & 31)];
    }
    __syncthreads();
    int l31 = l & 31, lh = l >> 5;
    bf16x8 v;
#pragma unroll
    for (int j = 0; j < 8; ++j) v[j] = (short)f2bf(tile[(lh * 8 + j) * 32 + l31]);
    unsigned short* dst = is2 ? W2F : W1F;
    *(bf16x8*)(dst + ((size_t)bj * 64 + l) * 8) = v;
  } else {
    const int r = (bid - 2560) * 4 + (tid >> 6);
    if (r > 1024) return;
    const int l = tid & 63;
    const float* src = (r < 1024) ? (Wmh + (size_t)r * 1024) : bmh;
    int nh = l >> 3, e = l & 7;
    float acc = 0.f;
    for (int d = 0; d < 128; ++d) acc = fmaf(src[nh * 128 + d], Wr[d * 8 + e], acc);
    Wc[(size_t)r * 64 + l] = acc;
  }
}

// ---------------- router pass 1: split-K partial logits + x_bf -------------
__global__ __launch_bounds__(256) void router_partial(
    const float* __restrict__ x, const float* __restrict__ Wc,
    float* __restrict__ part, unsigned short* __restrict__ x_bf,
    int* __restrict__ perm, float* __restrict__ gateb) {
  const int tid = threadIdx.x;
  const int kc = blockIdx.x, rb = blockIdx.y;
  int gi = (rb * 8 + kc) * 256 + tid;
  if (gi < NSLOT) { perm[gi] = 0; gateb[gi] = 0.f; }

  __shared__ float xs[32][128];    // 16 KB
  __shared__ float wcs[128][64];   // 32 KB
  const int r0 = rb * 32, k0 = kc * 128;

  for (int f = tid; f < 1024; f += 256) {
    int row = f >> 5, j4 = (f & 31) * 4;
    float4 v = *(const float4*)&x[(size_t)(r0 + row) * 1024 + k0 + j4];
    *(float4*)&xs[row][j4] = v;
    u16x4 o;
    o.x = f2bf(v.x); o.y = f2bf(v.y); o.z = f2bf(v.z); o.w = f2bf(v.w);
    *(u16x4*)&x_bf[(size_t)(r0 + row) * 1024 + k0 + j4] = o;
  }
  {
    const float4* src = (const float4*)(Wc + (size_t)k0 * 64);
    float4* dst = (float4*)&wcs[0][0];
    for (int f = tid; f < 2048; f += 256) dst[f] = src[f];
  }
  __syncthreads();

  const int col = tid & 63, rg = tid >> 6;
  float a[8] = {0.f, 0.f, 0.f, 0.f, 0.f, 0.f, 0.f, 0.f};
  for (int k4 = 0; k4 < 32; ++k4) {
    float4 xv[8];
#pragma unroll
    for (int i = 0; i < 8; ++i)
      xv[i] = *(const float4*)&xs[rg * 8 + i][k4 * 4];
#pragma unroll
    for (int u = 0; u < 4; ++u) {
      float wv = wcs[k4 * 4 + u][col];
#pragma unroll
      for (int i = 0; i < 8; ++i)
        a[i] = fmaf((&xv[i].x)[u], wv, a[i]);
    }
  }
#pragma unroll
  for (int i = 0; i < 8; ++i)
    part[(size_t)kc * 262144 + (size_t)(r0 + rg * 8 + i) * 64 + col] = a[i];
}

// ---------------- router pass 2: fixed-order reduce + top-2 + counts -------
__global__ __launch_bounds__(256) void router_reduce(
    const float* __restrict__ part, const float* __restrict__ Wc,
    int* __restrict__ tok_e, float* __restrict__ tok_g,
    int* __restrict__ ctrl) {
  __shared__ float lg[32][64];
  __shared__ int lcnt[8];
  const int tid = threadIdx.x;
  if (tid < 8) lcnt[tid] = 0;
  const int r0 = blockIdx.x * 32;
  const int col = tid & 63, rg = tid >> 6;
#pragma unroll
  for (int i = 0; i < 8; ++i) {
    size_t base = (size_t)(r0 + rg * 8 + i) * 64 + col;
    float s = Wc[65536 + col];
#pragma unroll
    for (int kc = 0; kc < 8; ++kc) s += part[(size_t)kc * 262144 + base];
    lg[rg * 8 + i][col] = s;
  }
  __syncthreads();
  {
    int row = tid >> 3, nh = tid & 7;
    float l[8];
#pragma unroll
    for (int e = 0; e < 8; ++e) l[e] = lg[row][nh * 8 + e];
    int i1 = 0; float v1 = l[0];
#pragma unroll
    for (int e = 1; e < 8; ++e) if (l[e] > v1) { v1 = l[e]; i1 = e; }
    int i2 = -1; float v2 = -1e30f;
#pragma unroll
    for (int e = 0; e < 8; ++e) if (e != i1 && l[e] > v2) { v2 = l[e]; i2 = e; }
    float g1 = 1.f / (1.f + __expf(v2 - v1));
    float g2 = 1.f - g1;
    size_t t = (size_t)(r0 + row) * 8 + nh;
    tok_e[t * 2] = i1; tok_e[t * 2 + 1] = i2;
    tok_g[t * 2] = g1; tok_g[t * 2 + 1] = g2;
    atomicAdd(&lcnt[i1], 1);
    atomicAdd(&lcnt[i2], 1);
  }
  __syncthreads();
  if (tid < 8 && lcnt[tid])
    atomicAdd(&ctrl[CTRL_CNT + tid], lcnt[tid]);
}

// ---------------- assign (unchanged) ----------------
__global__ __launch_bounds__(256) void assign_kernel(
    const int* __restrict__ tok_e, const float* __restrict__ tok_g,
    int* __restrict__ ctrl, int* __restrict__ perm,
    float* __restrict__ gateb, int* __restrict__ tok_slot) {
  __shared__ int lcnt[8], lbase[8];
  if (threadIdx.x < 8) lcnt[threadIdx.x] = 0;
  __syncthreads();
  int t = blockIdx.x * 256 + threadIdx.x;
  int e0 = tok_e[t * 2], e1 = tok_e[t * 2 + 1];
  int p0 = atomicAdd(&lcnt[e0], 1);
  int p1 = atomicAdd(&lcnt[e1], 1);
  __syncthreads();
  if (threadIdx.x < 8)
    lbase[threadIdx.x] = atomicAdd(&ctrl[CTRL_CUR + threadIdx.x], lcnt[threadIdx.x]);
  __syncthreads();
  int off0 = 0, off1 = 0, acc = 0;
#pragma unroll
  for (int i = 0; i < 8; ++i) {
    int cnt = ctrl[CTRL_CNT + i];
    if (i == e0) off0 = acc;
    if (i == e1) off1 = acc;
    acc += (cnt + 127) & ~127;
  }
  int s0 = off0 + lbase[e0] + p0;
  int s1 = off1 + lbase[e1] + p1;
  perm[s0] = t; perm[s1] = t;
  gateb[s0] = tok_g[t * 2]; gateb[s1] = tok_g[t * 2 + 1];
  tok_slot[t * 2] = s0; tok_slot[t * 2 + 1] = s1;
}

// ---------------- GEMM: C[M][N] = A[M][K](bf16) @ Bt[N][K](bf16)^T + bias --
// 128x64 tile, BK=64, 512 threads = 8 waves (4 row x 2 col, 32x32 wave
// tiles), grid (M/128, N/64) = 512 blocks = 2 blocks/CU = 4 waves/SIMD.
// A_GATHER=1: A row r, col k = ybuf[s0][k%128]+ybuf[s1][k%128], tok=r*8+k/128.
template <int OUT_BF16, int A_GATHER>
__global__ __launch_bounds__(512, 4) void gemm_bt(
    const unsigned short* __restrict__ A, const unsigned short* __restrict__ Bt,
    const float* __restrict__ bias, void* __restrict__ Cout,
    int M, int N, int K,
    const unsigned short* __restrict__ ybuf, const int* __restrict__ tok_slot) {
  __shared__ __align__(16) unsigned short As[2][128 * 64];
  __shared__ __align__(16) unsigned short Bs[2][64 * 64];
  const int tid = threadIdx.x, lane = tid & 63, w = tid >> 6;
  const int wr = w >> 1, wc = w & 1;          // wr 0..3 (32-row), wc 0..1 (32-col)
  const int m0 = blockIdx.x * 128, n0 = blockIdx.y * 64;
  const int l15 = lane & 15, lhi = lane >> 4;

  f32x4 acc[2][2];
#pragma unroll
  for (int n = 0; n < 2; ++n) {
    float bv = bias[n0 + wc * 32 + n * 16 + l15];
#pragma unroll
    for (int m = 0; m < 2; ++m) acc[m][n] = (f32x4){bv, bv, bv, bv};
  }

  const int rowi = tid >> 3;       // 0..63
  const int segi = (tid & 7) * 8;  // k offset
  const int NT = K >> 6;

  auto stage = [&](int buf, int kt) {
    const int k0 = kt * 64;
    if constexpr (A_GATHER) {
#pragma unroll
      for (int r = 0; r < 2; ++r) {
        int arow = m0 + r * 64 + rowi;
        int k = k0 + segi;
        int tok = arow * 8 + (k >> 7);
        int hd = k & 127;
        int s0 = tok_slot[tok * 2], s1 = tok_slot[tok * 2 + 1];
        bf16x8 va = *(const bf16x8*)(ybuf + (size_t)s0 * 128 + hd);
        bf16x8 vb = *(const bf16x8*)(ybuf + (size_t)s1 * 128 + hd);
        bf16x8 vs;
#pragma unroll
        for (int j = 0; j < 8; ++j)
          vs[j] = (short)f2bf(bf2f((unsigned short)va[j]) + bf2f((unsigned short)vb[j]));
        *(bf16x8*)&As[buf][r * 4096 + tid * 8] = vs;
      }
    } else {
#pragma unroll
      for (int r = 0; r < 2; ++r)
        gload_lds16(A + (size_t)(m0 + r * 64 + rowi) * K + k0 + segi,
                    &As[buf][r * 4096 + w * 512]);
    }
    gload_lds16(Bt + (size_t)(n0 + rowi) * K + k0 + segi,
                &Bs[buf][w * 512]);
  };

  stage(0, 0);
  asm volatile("s_waitcnt vmcnt(0)" ::: "memory");
  __syncthreads();
  int cur = 0;
  for (int t = 0; t < NT; ++t) {
    if (t + 1 < NT) stage(cur ^ 1, t + 1);
#pragma unroll
    for (int ks = 0; ks < 64; ks += 32) {
      bf16x8 af[2], bb[2];
#pragma unroll
      for (int m = 0; m < 2; ++m)
        af[m] = *(const bf16x8*)&As[cur][(wr * 32 + m * 16 + l15) * 64 + ks + lhi * 8];
#pragma unroll
      for (int n = 0; n < 2; ++n)
        bb[n] = *(const bf16x8*)&Bs[cur][(wc * 32 + n * 16 + l15) * 64 + ks + lhi * 8];
#pragma unroll
      for (int m = 0; m < 2; ++m)
#pragma unroll
        for (int n = 0; n < 2; ++n)
          acc[m][n] = __builtin_amdgcn_mfma_f32_16x16x32_bf16(af[m], bb[n], acc[m][n], 0, 0, 0);
    }
    asm volatile("s_waitcnt vmcnt(0)" ::: "memory");
    __syncthreads();
    cur ^= 1;
  }
#pragma unroll
  for (int m = 0; m < 2; ++m) {
#pragma unroll
    for (int n = 0; n < 2; ++n) {
      int col = n0 + wc * 32 + n * 16 + l15;
#pragma unroll
      for (int j = 0; j < 4; ++j) {
        int row = m0 + wr * 32 + m * 16 + lhi * 4 + j;
        if (OUT_BF16)
          ((unsigned short*)Cout)[(size_t)row * N + col] = f2bf(acc[m][n][j]);
        else
          ((float*)Cout)[(size_t)row * N + col] = acc[m][n][j];
      }
    }
  }
}

// ---------------- sparse FFN v10: v3 body + 3-buf counted vmcnt ------------
__global__ __launch_bounds__(256, 3) void ffn_sparse_v10(
    const unsigned short* __restrict__ hbf,   // [32768][128]
    const int* __restrict__ ctrl,
    const int* __restrict__ perm,             // [NSLOT]
    const float* __restrict__ gateb,          // [NSLOT]
    const unsigned short* __restrict__ W1F,   // [e][16][8][64][8]
    const float* __restrict__ b1,             // [8][512]
    const unsigned short* __restrict__ W2F,   // [e][16][2][4][64][8]
    const float* __restrict__ b2,             // [8][128]
    unsigned short* __restrict__ ybuf) {      // [NSLOT][128]
  int e = -1;
  {
    int accT = 0;
#pragma unroll
    for (int i = 0; i < 8; ++i) {
      int tiles = (ctrl[CTRL_CNT + i] + 127) >> 7;
      if (e < 0 && (int)blockIdx.x < accT + tiles) e = i;
      accT += tiles;
    }
  }
  if (e < 0) return;
  __shared__ __align__(16) unsigned short W1c[3][4096];
  __shared__ __align__(16) unsigned short W2c[3][4096];
  __shared__ float b1_s[512];
  __shared__ float b2_s[128];
  const int tid = threadIdx.x, l = tid & 63, w = tid >> 6;
  const int l31 = l & 31, lh = l >> 5;
  const int slot = blockIdx.x * 128 + w * 32 + l31;
  const int prow = perm[slot];
  const float gate = gateb[slot];

  bf16x8 hreg[8];
  const unsigned short* hsrc = hbf + (size_t)prow * 128 + lh * 8;
#pragma unroll
  for (int kk = 0; kk < 8; ++kk)
    hreg[kk] = *(const bf16x8*)(hsrc + kk * 16);

  if (tid < 128) ((float4*)b1_s)[tid] = ((const float4*)(b1 + e * 512))[tid];
  if (tid < 32)  ((float4*)b2_s)[tid] = ((const float4*)(b2 + e * 128))[tid];

  const unsigned short* W1e = W1F + (size_t)e * 65536;
  const unsigned short* W2e = W2F + (size_t)e * 65536;
  auto stage = [&](int buf, int ft) {
#pragma unroll
    for (int r = 0; r < 2; ++r) {
      gload_lds16(W1e + (size_t)ft * 4096 + (size_t)(r * 256 + tid) * 8,
                  &W1c[buf][r * 2048 + w * 512]);
      gload_lds16(W2e + (size_t)ft * 4096 + (size_t)(r * 256 + tid) * 8,
                  &W2c[buf][r * 2048 + w * 512]);
    }
  };

  stage(0, 0);
  stage(1, 1);
  asm volatile("s_waitcnt vmcnt(4)" ::: "memory");
  __builtin_amdgcn_s_barrier();

  f32x16 yacc[4] = {};
  for (int ft = 0; ft < 16; ++ft) {
    const int buf = ft % 3;
    if (ft + 2 < 16) stage((ft + 2) % 3, ft + 2);
    const float4* b14 = (const float4*)b1_s;
    float4 q0 = b14[ft * 8 + lh];
    float4 q1 = b14[ft * 8 + lh + 2];
    float4 q2 = b14[ft * 8 + lh + 4];
    float4 q3 = b14[ft * 8 + lh + 6];
    f32x16 aacc = {q0.x, q0.y, q0.z, q0.w, q1.x, q1.y, q1.z, q1.w,
                   q2.x, q2.y, q2.z, q2.w, q3.x, q3.y, q3.z, q3.w};
#pragma unroll
    for (int kk = 0; kk < 8; ++kk) {
      bf16x8 a1 = *(const bf16x8*)&W1c[buf][(kk * 64 + l) * 8];
      aacc = __builtin_amdgcn_mfma_f32_32x32x16_bf16(a1, hreg[kk], aacc, 0, 0, 0);
    }
    float ge[16];
#pragma unroll
    for (int r = 0; r < 16; ++r) {
      float v = aacc[r];
      float s2 = v * v;
      float q = fmaf(0.1029432f, s2, 2.3022078f);
      float E = exp2f(v * q);
      float rc = __builtin_amdgcn_rcpf(E + 1.f);
      ge[r] = fmaf(-v, rc, v) * gate;
    }
    unsigned pk[8];
#pragma unroll
    for (int p = 0; p < 8; ++p) {
      unsigned r;
      asm("v_cvt_pk_bf16_f32 %0, %1, %2" : "=v"(r) : "v"(ge[2 * p]), "v"(ge[2 * p + 1]));
      pk[p] = r;
    }
    asm volatile("v_permlane32_swap_b32 %0, %1" : "+v"(pk[0]), "+v"(pk[2]));
    asm volatile("v_permlane32_swap_b32 %0, %1" : "+v"(pk[1]), "+v"(pk[3]));
    asm volatile("v_permlane32_swap_b32 %0, %1" : "+v"(pk[4]), "+v"(pk[6]));
    asm volatile("v_permlane32_swap_b32 %0, %1" : "+v"(pk[5]), "+v"(pk[7]));
    typedef __attribute__((ext_vector_type(4))) unsigned u32x4;
    u32x4 f0 = {pk[0], pk[1], pk[2], pk[3]};
    u32x4 f1 = {pk[4], pk[5], pk[6], pk[7]};
    bf16x8 act0 = __builtin_bit_cast(bf16x8, f0);
    bf16x8 act1 = __builtin_bit_cast(bf16x8, f1);
#pragma unroll
    for (int ht = 0; ht < 4; ++ht) {
      bf16x8 a20 = *(const bf16x8*)&W2c[buf][(ht * 64 + l) * 8];
      yacc[ht] = __builtin_amdgcn_mfma_f32_32x32x16_bf16(a20, act0, yacc[ht], 0, 0, 0);
      bf16x8 a21 = *(const bf16x8*)&W2c[buf][((4 + ht) * 64 + l) * 8];
      yacc[ht] = __builtin_amdgcn_mfma_f32_32x32x16_bf16(a21, act1, yacc[ht], 0, 0, 0);
    }
    if (ft < 15) {
      if (ft + 2 < 16) {
        asm volatile("s_waitcnt vmcnt(4)" ::: "memory");
      } else {
        asm volatile("s_waitcnt vmcnt(0)" ::: "memory");
      }
      __builtin_amdgcn_s_barrier();
    }
  }
#pragma unroll
  for (int ht = 0; ht < 4; ++ht) {
#pragma unroll
    for (int rp = 0; rp < 8; ++rp) {
      int fr = ((2 * rp) & 3) + 8 * (rp >> 1) + 4 * lh;
      int hd = ht * 32 + fr;
      float2 bb2 = *(const float2*)&b2_s[hd];
      float v0 = fmaf(gate, bb2.x, yacc[ht][2 * rp]);
      float v1 = fmaf(gate, bb2.y, yacc[ht][2 * rp + 1]);
      unsigned pw;
      asm("v_cvt_pk_bf16_f32 %0, %1, %2" : "=v"(pw) : "v"(v0), "v"(v1));
      *(unsigned*)(ybuf + (size_t)slot * 128 + hd) = pw;
    }
  }
}

// ---------------------------------------------------------------------------
extern "C" void kernel_launch(void* const* d_in, const int* in_sizes, int n_in,
                              void* d_out, int out_size, void* d_ws, size_t ws_size,
                              hipStream_t stream) {
  const float* x       = (const float*)d_in[0];
  const float* W_mh    = (const float*)d_in[1];
  const float* b_mh    = (const float*)d_in[2];
  const float* W_merge = (const float*)d_in[3];
  const float* b_merge = (const float*)d_in[4];
  const float* W_rout  = (const float*)d_in[5];
  const float* W1      = (const float*)d_in[6];
  const float* b1      = (const float*)d_in[7];
  const float* W2      = (const float*)d_in[8];
  const float* b2      = (const float*)d_in[9];
  float* out = (float*)d_out;

  char* ws = (char*)d_ws;
  size_t off = 0;
  auto alloc = [&](size_t bytes) {
    void* p = ws + off;
    off = (off + bytes + 255) & ~(size_t)255;
    return p;
  };
  unsigned short* x_bf  = (unsigned short*)alloc((size_t)4096 * 1024 * 2);
  unsigned short* Wmh_t = (unsigned short*)alloc((size_t)1024 * 1024 * 2);
  unsigned short* Wmg_t = (unsigned short*)alloc((size_t)1024 * 1024 * 2);
  unsigned short* W1F   = (unsigned short*)alloc((size_t)8 * 512 * 128 * 2);
  unsigned short* W2F   = (unsigned short*)alloc((size_t)8 * 512 * 128 * 2);
  unsigned short* h_bf  = (unsigned short*)alloc((size_t)4096 * 1024 * 2);
  unsigned short* ybuf  = (unsigned short*)alloc((size_t)NSLOT * 128 * 2);
  float* Wc             = (float*)alloc((size_t)1025 * 64 * 4);
  float* part           = (float*)alloc((size_t)8 * 4096 * 64 * 4);
  int*   ctrl           = (int*)alloc(4096);
  int*   tok_e          = (int*)alloc((size_t)32768 * 2 * 4);
  float* tok_g          = (float*)alloc((size_t)32768 * 2 * 4);
  int*   tok_slot       = (int*)alloc((size_t)32768 * 2 * 4);
  int*   perm           = (int*)alloc((size_t)NSLOT * 4);
  float* gateb          = (float*)alloc((size_t)NSLOT * 4);

  prep_all<<<2817, 256, 0, stream>>>(W_mh, Wmh_t, W_merge, Wmg_t,
                                     W1, W2, W1F, W2F, b_mh, W_rout, Wc, ctrl);
  router_partial<<<dim3(8, 128), 256, 0, stream>>>(x, Wc, part, x_bf, perm, gateb);
  router_reduce<<<128, 256, 0, stream>>>(part, Wc, tok_e, tok_g, ctrl);
  assign_kernel<<<128, 256, 0, stream>>>(tok_e, tok_g, ctrl, perm, gateb, tok_slot);
  gemm_bt<1, 0><<<dim3(32, 16), 512, 0, stream>>>(x_bf, Wmh_t, b_mh, (void*)h_bf,
                                                  4096, 1024, 1024, nullptr, nullptr);
  ffn_sparse_v10<<<NTILE_MAX, 256, 0, stream>>>(h_bf, ctrl, perm, gateb, W1F, b1, W2F, b2, ybuf);
  gemm_bt<0, 1><<<dim3(32, 16), 512, 0, stream>>>(nullptr, Wmg_t, b_merge, (void*)out,
                                                  4096, 1024, 1024, ybuf, tok_slot);
}